// Round 1
// baseline (934.750 us; speedup 1.0000x reference)
//
#include <hip/hip_runtime.h>

// MemoryReader: S = (2*K^T Q - |k|^2)/8, P = softmax_n(S), mem = V P ; out = [mem, qv]
// B=16, CK=64, CV=512, N=HW=3136 (pad to 3200)

#define B_   16
#define CK_  64
#define CV_  512
#define N_   3136
#define NPAD 3200
#define TM   64      // query tile per workgroup
#define TN   128     // memory tile per iteration
#define NITER 25     // ceil(3136/128) -> covers padded 3200

typedef __bf16 bf16_t;
typedef bf16_t bf16x8 __attribute__((ext_vector_type(8)));
typedef bf16_t bf16x4 __attribute__((ext_vector_type(4)));
typedef float  f32x16 __attribute__((ext_vector_type(16)));

#define SCALE_DOT 0.36067376022224085f  // 0.25 * log2(e)

// ---- prep 1: K,Q -> transposed bf16 [B][n][c], plus a2[n] = |k_n|^2 * 0.125 * log2(e)
__global__ __launch_bounds__(256) void prep_kq(const float* __restrict__ mk,
                                               const float* __restrict__ qk,
                                               bf16_t* __restrict__ Kt,
                                               bf16_t* __restrict__ Qt,
                                               float* __restrict__ a2) {
  int idx = blockIdx.x * 256 + threadIdx.x;       // 0 .. 16*3200-1 (grid exact)
  int b = idx / NPAD, n = idx % NPAD;
  bool valid = n < N_;
  float ss = 0.f;
  const float* mkp = mk + (size_t)b * CK_ * N_ + n;
  const float* qkp = qk + (size_t)b * CK_ * N_ + n;
  #pragma unroll
  for (int s = 0; s < 8; s++) {
    bf16x8 kv, qv8;
    #pragma unroll
    for (int j = 0; j < 8; j++) {
      int c = 8 * s + j;
      float kx = valid ? mkp[(size_t)c * N_] : 0.f;
      float qx = valid ? qkp[(size_t)c * N_] : 0.f;
      ss += kx * kx;
      kv[j] = (bf16_t)kx;
      qv8[j] = (bf16_t)qx;
    }
    *(bf16x8*)(Kt + (size_t)idx * CK_ + 8 * s) = kv;
    *(bf16x8*)(Qt + (size_t)idx * CK_ + 8 * s) = qv8;
  }
  a2[idx] = ss * 0.125f * 1.4426950408889634f;
}

// ---- prep 2: V -> bf16 [B][c][n], n padded to 3200 (pad zeroed)
__global__ __launch_bounds__(256) void prep_v(const float* __restrict__ mv,
                                              bf16_t* __restrict__ V) {
  int idx = blockIdx.x * 256 + threadIdx.x;       // over 16*512*400 (grid exact)
  int row = idx / (NPAD / 8);
  int n = (idx % (NPAD / 8)) * 8;
  bf16x8 o;
  if (n < N_) {
    const float* p = mv + (size_t)row * N_ + n;
    #pragma unroll
    for (int j = 0; j < 8; j++) o[j] = (bf16_t)p[j];
  } else {
    #pragma unroll
    for (int j = 0; j < 8; j++) o[j] = (bf16_t)0.f;
  }
  *(bf16x8*)(V + (size_t)row * NPAD + n) = o;
}

// ---- main fused kernel: one workgroup = (batch b, 64-query tile m0), 8 waves
// S-phase: wave w computes 32x32 tile at (n-slice w&3, m-slice w>>2) of the
//          [128 x 64] score tile via mfma_f32_32x32x16_bf16; P=exp2(s*log2e)
//          written bf16 to LDS [m][n] (stride 136 = odd multiple of 16B).
// O-phase: wave w owns channels c in [64w, 64w+64); acc[2][2] of 32x32 tiles,
//          A = V (16B global loads), B = P (ds_read_b128).
// No online max: scores provably <= |q|^2/8 (~16), fp32 exp cannot overflow.
__global__ __launch_bounds__(512) void attn_main(const bf16_t* __restrict__ Kt,
                                                 const bf16_t* __restrict__ Qt,
                                                 const float* __restrict__ a2,
                                                 const bf16_t* __restrict__ V,
                                                 float* __restrict__ out) {
  const int b  = blockIdx.x / 49;
  const int m0 = (blockIdx.x % 49) * TM;
  const int tid  = threadIdx.x;
  const int w    = tid >> 6;
  const int lane = tid & 63;
  const int l32  = lane & 31;
  const int h    = lane >> 5;
  const int g    = w >> 2;   // S-phase m-slice (0..1)
  const int i    = w & 3;    // S-phase n-slice (0..3)

  __shared__ bf16_t Plds[64][136];
  __shared__ float  Llds[8][32];
  __shared__ float  Linv[64];

  // loop-invariant Q fragments: B[k=8h+j][m'=l32] = Qt[m0+32g+l32][16s+8h+j]
  const bf16x8* qrow = (const bf16x8*)(Qt + ((size_t)b * NPAD + m0 + 32 * g + l32) * CK_);
  bf16x8 qfrag[4];
  #pragma unroll
  for (int s = 0; s < 4; s++) qfrag[s] = qrow[2 * s + h];

  f32x16 acc[2][2];
  #pragma unroll
  for (int cb = 0; cb < 2; cb++)
    #pragma unroll
    for (int mb = 0; mb < 2; mb++)
      #pragma unroll
      for (int r = 0; r < 16; r++) acc[cb][mb][r] = 0.f;

  float Lpart = 0.f;
  const float*  a2b = a2 + (size_t)b * NPAD;
  const bf16_t* Vb  = V + ((size_t)b * CV_ + 64 * w) * NPAD;

  for (int iter = 0; iter < NITER; iter++) {
    const int nb = iter * TN;
    const int n0 = nb + 32 * i;

    // --- S: D[n',m'] = sum_c Kt[n0+n'][c] * Qt[m0+32g+m'][c]
    f32x16 sacc;
    #pragma unroll
    for (int r = 0; r < 16; r++) sacc[r] = 0.f;
    const bf16x8* krow = (const bf16x8*)(Kt + ((size_t)b * NPAD + n0 + l32) * CK_);
    #pragma unroll
    for (int s = 0; s < 4; s++) {
      bf16x8 kf = krow[2 * s + h];
      sacc = __builtin_amdgcn_mfma_f32_32x32x16_bf16(kf, qfrag[s], sacc, 0, 0, 0);
    }

    __syncthreads();  // previous O-phase finished reading Plds

    // --- P = exp2(dot*SCALE_DOT - a2[n]); pack bf16 -> LDS; accumulate col sums
    #pragma unroll
    for (int t = 0; t < 4; t++) {
      bf16x4 pk;
      #pragma unroll
      for (int q = 0; q < 4; q++) {
        int r = 8 * t + 4 * h + q;          // C/D row for reg 4t+q
        int n = n0 + r;
        float vv = sacc[4 * t + q] * SCALE_DOT - a2b[n];
        float p = (n < N_) ? __builtin_amdgcn_exp2f(vv) : 0.f;
        Lpart += p;
        pk[q] = (bf16_t)p;
      }
      *(bf16x4*)(&Plds[32 * g + l32][32 * i + 8 * t + 4 * h]) = pk;
    }

    __syncthreads();  // P tile ready

    // --- O: acc[cb][mb] += V[64w+32cb+row][nb+k] * P[nb+k][32mb+col]
    const bf16x8* vrow0 = (const bf16x8*)(Vb + (size_t)l32 * NPAD + nb);
    const bf16x8* vrow1 = (const bf16x8*)(Vb + (size_t)(32 + l32) * NPAD + nb);
    #pragma unroll
    for (int t = 0; t < 8; t++) {
      bf16x8 vf0 = vrow0[2 * t + h];
      bf16x8 vf1 = vrow1[2 * t + h];
      bf16x8 pf0 = *(const bf16x8*)(&Plds[l32][16 * t + 8 * h]);
      bf16x8 pf1 = *(const bf16x8*)(&Plds[32 + l32][16 * t + 8 * h]);
      acc[0][0] = __builtin_amdgcn_mfma_f32_32x32x16_bf16(vf0, pf0, acc[0][0], 0, 0, 0);
      acc[0][1] = __builtin_amdgcn_mfma_f32_32x32x16_bf16(vf0, pf1, acc[0][1], 0, 0, 0);
      acc[1][0] = __builtin_amdgcn_mfma_f32_32x32x16_bf16(vf1, pf0, acc[1][0], 0, 0, 0);
      acc[1][1] = __builtin_amdgcn_mfma_f32_32x32x16_bf16(vf1, pf1, acc[1][1], 0, 0, 0);
    }
  }

  // --- column-sum (softmax denominator) reduction
  Lpart += __shfl_xor(Lpart, 32, 64);
  if (h == 0) Llds[w][l32] = Lpart;
  __syncthreads();
  if (tid < 64) {
    int gg = tid >> 5;
    float s = 0.f;
    #pragma unroll
    for (int ww = 0; ww < 4; ww++) s += Llds[4 * gg + ww][tid & 31];
    Linv[tid] = 1.0f / s;
  }
  __syncthreads();

  // --- epilogue: normalize + store fp32
  #pragma unroll
  for (int cb = 0; cb < 2; cb++) {
    #pragma unroll
    for (int mb = 0; mb < 2; mb++) {
      float rl = Linv[32 * mb + l32];
      #pragma unroll
      for (int reg = 0; reg < 16; reg++) {
        int r = (reg & 3) + 8 * (reg >> 2) + 4 * h;
        int c = 64 * w + 32 * cb + r;
        out[((size_t)b * CV_ + c) * N_ + m0 + 32 * mb + l32] = acc[cb][mb][reg] * rl;
      }
    }
  }
}

extern "C" void kernel_launch(void* const* d_in, const int* in_sizes, int n_in,
                              void* d_out, int out_size, void* d_ws, size_t ws_size,
                              hipStream_t stream) {
  const float* mk = (const float*)d_in[0];
  const float* qk = (const float*)d_in[1];
  const float* mv = (const float*)d_in[2];
  const float* qv = (const float*)d_in[3];
  float* out = (float*)d_out;

  // workspace layout (bytes):
  //   Kt  [16][3200][64] bf16 : 6,553,600   @ 0
  //   Qt  [16][3200][64] bf16 : 6,553,600   @ 6,553,600
  //   a2  [16][3200]     f32  :   204,800   @ 13,107,200
  //   V   [16][512][3200]bf16 : 52,428,800  @ 13,312,000
  // total ~62.7 MB
  char* ws = (char*)d_ws;
  bf16_t* Kt = (bf16_t*)(ws);
  bf16_t* Qt = (bf16_t*)(ws + 6553600);
  float*  a2 = (float*)(ws + 13107200);
  bf16_t* V  = (bf16_t*)(ws + 13312000);

  prep_kq<<<dim3((B_ * NPAD) / 256), dim3(256), 0, stream>>>(mk, qk, Kt, Qt, a2);
  prep_v<<<dim3((B_ * CV_ * (NPAD / 8)) / 256), dim3(256), 0, stream>>>(mv, V);
  attn_main<<<dim3(B_ * 49), dim3(512), 0, stream>>>(Kt, Qt, a2, V, out);

  // output 1: qv passthrough
  hipMemcpyAsync(out + (size_t)B_ * CV_ * N_, qv,
                 (size_t)B_ * CV_ * N_ * sizeof(float),
                 hipMemcpyDeviceToDevice, stream);
}